// Round 1
// baseline (283.447 us; speedup 1.0000x reference)
//
#include <hip/hip_runtime.h>
#include <hip/hip_bf16.h>

#define B_ 32
#define T_ 40
#define P_ 256
#define V_ 4096
#define D_ 256
#define DINO_ 384
#define H_ 4
#define L_ 2
#define HD_ 64
#define DFF_ 1024
#define EPS_ 1e-5f

typedef __bf16 bf16;
typedef __bf16 bf16x8 __attribute__((ext_vector_type(8)));
typedef float f32x4 __attribute__((ext_vector_type(4)));

// bf16 weight arena offsets (elements)
#define OFF_QKV 0            // 2 x 768*256
#define OFF_OUTW 393216      // 2 x 256*256
#define OFF_W1 524288        // 2 x 1024*256
#define OFF_W2 1048576       // 2 x 256*1024
#define OFF_FUS 1572864      // 256*640
#define WB_TOTAL 1736704
#define CONV_BLOCKS 848      // WB_TOTAL / 2048
#define PAT_BLOCKS 1536      // 32*256*384 / 2048

__device__ __forceinline__ bf16x8 cvt8(const float* p) {
  float4 f0 = *(const float4*)p;
  float4 f1 = *(const float4*)(p + 4);
  bf16x8 v;
  v[0] = (bf16)f0.x; v[1] = (bf16)f0.y; v[2] = (bf16)f0.z; v[3] = (bf16)f0.w;
  v[4] = (bf16)f1.x; v[5] = (bf16)f1.y; v[6] = (bf16)f1.z; v[7] = (bf16)f1.w;
  return v;
}

// ---------------------------------------------------------------------------
// Generic 32x32-tile MFMA GEMM body, full-K LDS panel (single barrier per
// KP-chunk). ASRC: 0=f32 A, 1=bf16 A, 2=LN-fold(f32 A rows), 3=token-gather
// f32 rows, 4=shifted-LN-fold (cproj), 5=embed-fold (tok_emb+pos_emb).
// WF32: W staged from f32 (cvt). CW: 0 normal, 1 cw-even(+bias), 2 cw-odd.
// xout!=nullptr (ASRC 2/5): also write the staged fp32 rows (residual path).
// ---------------------------------------------------------------------------
template <int ASRC, int KP, int WF32, int OBF16, int RELU, int RESID, int CW>
__device__ __forceinline__ void gemm_body(
    bf16* As, bf16* Ws, const void* Av, const void* Wv, const float* bias,
    const float* resid, const float* aux0, const float* aux1,
    const int* tokens, float* xout, void* outv, int K, int lda, int ldw,
    int ldc, int bm, int bn) {
  const int LDP = KP + 8;
  const int tid = threadIdx.x;
  const int lane = tid & 63;
  const int wv = tid >> 6;
  const int mi = wv & 1, ni = wv >> 1;
  const int col = lane & 15, quad = lane >> 4;
  const int srow = tid >> 3, kc = (tid & 7) * 8;
  const int gm = bm + srow;
  f32x4 acc = {0.f, 0.f, 0.f, 0.f};

  if (ASRC == 2 || ASRC == 4) {
    // LN over the full 256-col row, 8 threads/row, staged straight to LDS.
    const int cg = (tid & 7) * 32;
    bool zero = false;
    long srcrow = gm;
    if (ASRC == 4) {
      if (gm % T_ == 0) zero = true;
      srcrow = gm - 1;
    }
    if (zero) {
      bf16x8 z8 = {};
#pragma unroll
      for (int i = 0; i < 4; ++i) *(bf16x8*)&As[srow * LDP + cg + i * 8] = z8;
    } else {
      const float* sp = (const float*)Av + srcrow * D_ + cg;
      float v[32];
      float sum = 0.f, ss = 0.f;
#pragma unroll
      for (int i = 0; i < 8; ++i) {
        float4 f = *(const float4*)(sp + i * 4);
        v[i * 4] = f.x; v[i * 4 + 1] = f.y; v[i * 4 + 2] = f.z; v[i * 4 + 3] = f.w;
        sum += f.x + f.y + f.z + f.w;
        ss += f.x * f.x + f.y * f.y + f.z * f.z + f.w * f.w;
      }
#pragma unroll
      for (int mk = 1; mk < 8; mk <<= 1) {
        sum += __shfl_xor(sum, mk);
        ss += __shfl_xor(ss, mk);
      }
      float mean = sum * (1.0f / D_);
      float inv = rsqrtf(ss * (1.0f / D_) - mean * mean + EPS_);
#pragma unroll
      for (int i = 0; i < 32; ++i) {
        float o = (v[i] - mean) * inv * aux0[cg + i] + aux1[cg + i];
        As[srow * LDP + cg + i] = (bf16)o;
        v[i] = o;
      }
      if (ASRC == 2 && xout) {
#pragma unroll
        for (int i = 0; i < 8; ++i)
          *(float4*)(xout + (long)gm * D_ + cg + i * 4) =
              make_float4(v[i * 4], v[i * 4 + 1], v[i * 4 + 2], v[i * 4 + 3]);
      }
    }
  } else if (ASRC == 5) {
    const int tok = tokens[gm];
    const float* te = (const float*)Av + (long)tok * D_;
    const float* pe = aux0 + (gm % T_) * D_;
#pragma unroll
    for (int c = 0; c < KP / 64; ++c) {
      int off = kc + 64 * c;
      float4 e0 = *(const float4*)(te + off), e1 = *(const float4*)(te + off + 4);
      float4 p0 = *(const float4*)(pe + off), p1 = *(const float4*)(pe + off + 4);
      float o0 = e0.x + p0.x, o1 = e0.y + p0.y, o2 = e0.z + p0.z, o3 = e0.w + p0.w;
      float o4 = e1.x + p1.x, o5 = e1.y + p1.y, o6 = e1.z + p1.z, o7 = e1.w + p1.w;
      bf16x8 vv;
      vv[0] = (bf16)o0; vv[1] = (bf16)o1; vv[2] = (bf16)o2; vv[3] = (bf16)o3;
      vv[4] = (bf16)o4; vv[5] = (bf16)o5; vv[6] = (bf16)o6; vv[7] = (bf16)o7;
      *(bf16x8*)&As[srow * LDP + off] = vv;
      if (xout) {
        *(float4*)(xout + (long)gm * D_ + off) = make_float4(o0, o1, o2, o3);
        *(float4*)(xout + (long)gm * D_ + off + 4) = make_float4(o4, o5, o6, o7);
      }
    }
  }

  const float* Af = (const float*)Av;
  const bf16* Ab = (const bf16*)Av;
  const float* Wf = (const float*)Wv;
  const bf16* Wb = (const bf16*)Wv;

  for (int kk0 = 0; kk0 < K; kk0 += KP) {
    if (ASRC == 0) {
#pragma unroll
      for (int c = 0; c < KP / 64; ++c)
        *(bf16x8*)&As[srow * LDP + kc + 64 * c] =
            cvt8(Af + (long)gm * lda + kk0 + kc + 64 * c);
    } else if (ASRC == 1) {
#pragma unroll
      for (int c = 0; c < KP / 64; ++c)
        *(bf16x8*)&As[srow * LDP + kc + 64 * c] =
            *(const bf16x8*)(Ab + (long)gm * lda + kk0 + kc + 64 * c);
    } else if (ASRC == 3) {
      const float* Ag = Af + (long)tokens[gm] * D_;
#pragma unroll
      for (int c = 0; c < KP / 64; ++c)
        *(bf16x8*)&As[srow * LDP + kc + 64 * c] = cvt8(Ag + kk0 + kc + 64 * c);
    }
    if (WF32) {
#pragma unroll
      for (int c = 0; c < KP / 64; ++c)
        *(bf16x8*)&Ws[srow * LDP + kc + 64 * c] =
            cvt8(Wf + (long)(bn + srow) * ldw + kk0 + kc + 64 * c);
    } else {
#pragma unroll
      for (int c = 0; c < KP / 64; ++c)
        *(bf16x8*)&Ws[srow * LDP + kc + 64 * c] =
            *(const bf16x8*)(Wb + (long)(bn + srow) * ldw + kk0 + kc + 64 * c);
    }
    __syncthreads();
#pragma unroll
    for (int ki = 0; ki < KP / 32; ++ki) {
      bf16x8 afr = *(const bf16x8*)&As[(mi * 16 + col) * LDP + ki * 32 + quad * 8];
      bf16x8 bfr = *(const bf16x8*)&Ws[(ni * 16 + col) * LDP + ki * 32 + quad * 8];
      acc = __builtin_amdgcn_mfma_f32_16x16x32_bf16(afr, bfr, acc, 0, 0, 0);
    }
    if (kk0 + KP < K) __syncthreads();
  }

  const int n = bn + ni * 16 + col;
  float bv = bias ? bias[n] : 0.0f;
#pragma unroll
  for (int r = 0; r < 4; ++r) {
    int m = bm + mi * 16 + quad * 4 + r;
    float val = acc[r] + bv;
    if (RESID) val += resid[(long)m * D_ + n];
    if (RELU) val = fmaxf(val, 0.0f);
    if (CW == 1) ((float*)outv)[(long)m * (2 * D_) + n * 2] = val;
    else if (CW == 2) ((float*)outv)[(long)m * (2 * D_) + n * 2 + 1] = val;
    else if (OBF16) ((bf16*)outv)[(long)m * ldc + n] = (bf16)val;
    else ((float*)outv)[(long)m * ldc + n] = val;
  }
}

// shared-memory shapes
struct AttnSM { float q[20][65]; float k[40][65]; float v[40][65]; float s[20][41]; };
struct Gemm384SM { bf16 As[32 * 392]; bf16 Ws[32 * 392]; };
struct Gemm256SM { bf16 As[32 * 264]; bf16 Ws[32 * 264]; };
struct PrepSM { float tile[32][33]; };
union __align__(16) APSM { AttnSM a; Gemm384SM g; };
union __align__(16) PQSM { PrepSM p; Gemm256SM g; };

// ---- generic standalone GEMM wrapper --------------------------------------
template <int ASRC, int OBF16, int RELU, int RESID, int XW, int CW>
__global__ __launch_bounds__(256) void gemm_k(
    const void* __restrict__ Av, const void* __restrict__ Wv,
    const float* __restrict__ bias, const float* __restrict__ resid,
    const float* __restrict__ aux0, const float* __restrict__ aux1,
    const int* __restrict__ tokens, float* __restrict__ xw,
    void* __restrict__ outv, int K, int lda, int ldw, int ldc) {
  __shared__ Gemm256SM sm;
  gemm_body<ASRC, 256, 0, OBF16, RELU, RESID, CW>(
      sm.As, sm.Ws, Av, Wv, bias, resid, aux0, aux1, tokens,
      (XW && blockIdx.x == 0) ? xw : nullptr, outv, K, lda, ldw, ldc,
      blockIdx.y * 32, blockIdx.x * 32);
}

// ---- prep jobs merged with qkv0 (embed folded into staging) ---------------
__global__ __launch_bounds__(256) void pq_k(
    const int* __restrict__ tokens, const float* __restrict__ tok_emb,
    const float* __restrict__ pos_emb, float* __restrict__ x,
    const float* __restrict__ fus_w2, bf16* __restrict__ w2Tb,
    const float* __restrict__ qkv_w, const float* __restrict__ out_w,
    const float* __restrict__ w1, const float* __restrict__ w2,
    const float* __restrict__ fus_w1, bf16* __restrict__ wb,
    const float* __restrict__ patches, bf16* __restrict__ patb,
    const float* __restrict__ qkv_b, float* __restrict__ qkvbuf) {
  __shared__ PQSM sm;
  int bid = blockIdx.x;
  int tid = threadIdx.x;
  if (bid < 960) {
    // qkv layer 0: A = tok_emb gather + pos_emb (embed fold), W = fp32 qkv_w
    int bnb = bid % 24;
    gemm_body<5, 256, 1, 0, 0, 0, 0>(
        sm.g.As, sm.g.Ws, tok_emb, qkv_w, qkv_b, nullptr, pos_emb, nullptr,
        tokens, (bnb == 0) ? x : nullptr, qkvbuf, 256, 256, 256, 3 * D_,
        (bid / 24) * 32, bnb * 32);
    return;
  }
  int bi = bid - 960;
  if (bi < 64) {
    int bx = (bi & 7) * 32, by = (bi >> 3) * 32;
    int tx = tid & 31, ty = tid >> 5;  // 32 x 8
#pragma unroll
    for (int i = 0; i < 32; i += 8)
      sm.p.tile[ty + i][tx] = fus_w2[(by + ty + i) * D_ + bx + tx];
    __syncthreads();
#pragma unroll
    for (int i = 0; i < 32; i += 8)
      w2Tb[(bx + ty + i) * D_ + by + tx] = (bf16)sm.p.tile[tx][ty + i];
  } else if (bi < 64 + CONV_BLOCKS) {
    long f = (long)(bi - 64) * 2048 + tid * 8;
    const float* src;
    long off;
    if (f < OFF_OUTW)      { src = qkv_w;  off = f - OFF_QKV; }
    else if (f < OFF_W1)   { src = out_w;  off = f - OFF_OUTW; }
    else if (f < OFF_W2)   { src = w1;     off = f - OFF_W1; }
    else if (f < OFF_FUS)  { src = w2;     off = f - OFF_W2; }
    else                   { src = fus_w1; off = f - OFF_FUS; }
    *(bf16x8*)&wb[f] = cvt8(src + off);
  } else {
    long f = (long)(bi - 64 - CONV_BLOCKS) * 2048 + tid * 8;
    *(bf16x8*)&patb[f] = cvt8(patches + f);
  }
}

// ---- attention (+ optional co-launched pproj GEMM blocks) -----------------
__global__ __launch_bounds__(256) void attnp_k(
    const float* __restrict__ qkv, float* __restrict__ ctx,
    const bf16* __restrict__ patb, const bf16* __restrict__ fusb,
    float* __restrict__ pprojT) {
  __shared__ APSM sm;
  int bid = blockIdx.x;
  int tid = threadIdx.x;
  if (bid >= 256) {
    // pproj: C[e][p] = fus_w1_patch @ patb[b]^T  (independent of encoder)
    int g = bid - 256;
    int bn = (g & 7) * 32;
    int y = g >> 3;
    int bb = y >> 3, bm = (y & 7) * 32;
    gemm_body<1, 384, 0, 0, 0, 0, 0>(
        sm.g.As, sm.g.Ws, fusb, patb + (long)bb * P_ * DINO_, nullptr, nullptr,
        nullptr, nullptr, nullptr, nullptr, pprojT + (long)bb * D_ * P_, 384,
        640, DINO_, P_, bm, bn);
    return;
  }
  int h = bid & 3, b = (bid >> 2) & 31, zq = bid >> 7;
  int r0 = zq * 20;
  int lane = tid & 63, wv = tid >> 6;
  float (&q)[20][65] = sm.a.q;
  float (&k)[40][65] = sm.a.k;
  float (&v)[40][65] = sm.a.v;
  float (&s)[20][41] = sm.a.s;
  for (int idx = tid; idx < T_ * HD_; idx += 256) {
    int t = idx >> 6, d = idx & 63;
    long base = (long)(b * T_ + t) * (3 * D_) + h * HD_ + d;
    k[t][d] = qkv[base + D_];
    v[t][d] = qkv[base + 2 * D_];
    if (t < 20) q[t][d] = qkv[(long)(b * T_ + r0 + t) * (3 * D_) + h * HD_ + d];
  }
  __syncthreads();
  for (int idx = tid; idx < 20 * T_; idx += 256) {
    int i = idx / T_, j = idx - i * T_;
    if (j <= r0 + i) {
      float acc = 0.f;
#pragma unroll
      for (int d = 0; d < HD_; ++d) acc += q[i][d] * k[j][d];
      s[i][j] = acc * 0.125f;
    }
  }
  __syncthreads();
  for (int rr = wv; rr < 20; rr += 4) {
    int hi = r0 + rr;
    float val = (lane <= hi) ? s[rr][lane] : -1e30f;
    float mx = val;
#pragma unroll
    for (int mk = 1; mk < 64; mk <<= 1) mx = fmaxf(mx, __shfl_xor(mx, mk));
    float e = (lane <= hi)
                  ? __builtin_amdgcn_exp2f((val - mx) * 1.4426950408889634f)
                  : 0.f;
    float sum = e;
#pragma unroll
    for (int mk = 1; mk < 64; mk <<= 1) sum += __shfl_xor(sum, mk);
    float inv = __builtin_amdgcn_rcpf(sum);
    if (lane < T_) s[rr][lane] = e * inv;
  }
  __syncthreads();
  for (int idx = tid; idx < 20 * HD_; idx += 256) {
    int i = idx >> 6, d = idx & 63;
    int hi = r0 + i;
    float acc = 0.f;
    for (int j = 0; j <= hi; ++j) acc += s[i][j] * v[j][d];
    ctx[(long)(b * T_ + hi) * D_ + h * HD_ + d] = acc;
  }
}

// ---- out-proj(l=0) + weff co-launched -------------------------------------
__global__ __launch_bounds__(256) void ow_k(
    const float* __restrict__ attb, const bf16* __restrict__ Wout,
    const float* __restrict__ outb, const float* __restrict__ xres,
    float* __restrict__ sbuf, const float* __restrict__ cls_w,
    const bf16* __restrict__ w2Tb, const int* __restrict__ tokens,
    float* __restrict__ cw) {
  __shared__ Gemm256SM sm;
  int y = blockIdx.y;
  if (y < 40)
    gemm_body<0, 256, 0, 0, 0, 1, 0>(
        sm.As, sm.Ws, attb, Wout, outb, xres, nullptr, nullptr, nullptr,
        nullptr, sbuf, 256, 256, 256, 256, y * 32, blockIdx.x * 32);
  else
    gemm_body<3, 256, 0, 0, 0, 0, 2>(
        sm.As, sm.Ws, cls_w, w2Tb, nullptr, nullptr, nullptr, nullptr, tokens,
        nullptr, cw, 256, 256, 256, 256, (y - 40) * 32, blockIdx.x * 32);
}

// ---- final: out[b,p,t] = sigmoid(sum_e gelu(pp+cp)*we + beff) -------------
__global__ __launch_bounds__(256) void final_k(const float* __restrict__ pprojT,
                                               const float* __restrict__ cw,
                                               const int* __restrict__ tokens,
                                               const float* __restrict__ cls_w,
                                               const float* __restrict__ cls_b,
                                               const float* __restrict__ fus_b2,
                                               float* __restrict__ out) {
  __shared__ float2 cws[4][D_];
  int tid = threadIdx.x;
  int lane = tid & 63, wv = tid >> 6;
  int p = blockIdx.x * 64 + lane;
  int t = blockIdx.y * 4 + wv;
  int b = blockIdx.z;
  int mbase = b * T_ + blockIdx.y * 4;
  for (int idx = tid; idx < 4 * D_; idx += 256) {
    int tt = idx >> 8, e = idx & 255;
    cws[tt][e] = ((const float2*)cw)[(long)(mbase + tt) * D_ + e];
  }
  __syncthreads();

  int m = b * T_ + t;
  int tok = tokens[m];
  const float* cr = cls_w + (long)tok * D_;
  float bacc = 0.f;
#pragma unroll
  for (int i = 0; i < 4; ++i) bacc += cr[lane + i * 64] * fus_b2[lane + i * 64];
#pragma unroll
  for (int mk = 1; mk < 64; mk <<= 1) bacc += __shfl_xor(bacc, mk);
  float beff = bacc + cls_b[tok];

  const float* ppb = pprojT + (long)b * (D_ * P_);  // [e][p]
  float acc = 0.f;
#pragma unroll 8
  for (int e = 0; e < D_; ++e) {
    float pp = ppb[e * P_ + p];
    float2 c = cws[wv][e];
    float x = pp + c.x;
    float ex = __builtin_amdgcn_exp2f(-2.4554248f * x);  // -1.702*log2e
    float r = __builtin_amdgcn_rcpf(1.0f + ex);
    acc = fmaf(x * r, c.y, acc);
  }
  float logit = acc + beff;
  float es = __builtin_amdgcn_exp2f(-1.4426950408889634f * logit);
  out[(long)(b * P_ + p) * T_ + t] = __builtin_amdgcn_rcpf(1.0f + es);
}

extern "C" void kernel_launch(void* const* d_in, const int* in_sizes, int n_in, void* d_out,
                              int out_size, void* d_ws, size_t ws_size, hipStream_t stream) {
  const float* patches = (const float*)d_in[0];
  const int* tokens = (const int*)d_in[1];
  const float* tok_emb = (const float*)d_in[2];
  const float* pos_emb = (const float*)d_in[3];
  const float* qkv_w = (const float*)d_in[4];
  const float* qkv_b = (const float*)d_in[5];
  const float* out_w = (const float*)d_in[6];
  const float* out_b = (const float*)d_in[7];
  const float* ln1_s = (const float*)d_in[8];
  const float* ln1_b = (const float*)d_in[9];
  const float* w1 = (const float*)d_in[10];
  const float* b1 = (const float*)d_in[11];
  const float* w2 = (const float*)d_in[12];
  const float* b2 = (const float*)d_in[13];
  const float* ln2_s = (const float*)d_in[14];
  const float* ln2_b = (const float*)d_in[15];
  const float* fus_w1 = (const float*)d_in[16];
  const float* fus_b1 = (const float*)d_in[17];
  const float* fus_w2 = (const float*)d_in[18];
  const float* fus_b2 = (const float*)d_in[19];
  const float* cls_w = (const float*)d_in[20];
  const float* cls_b = (const float*)d_in[21];
  float* out = (float*)d_out;

  const int MT = B_ * T_;  // 1280
  float* x = (float*)d_ws;                     // 1280*256 (embed / LN outs)
  float* qkvbuf = x + MT * D_;                 // 1280*768
  float* attbuf = qkvbuf + MT * 3 * D_;        // 1280*256
  float* s = attbuf + MT * D_;                 // 1280*256 (residual sums)
  float* pprojT = s + MT * D_;                 // 32*256*256 [b][e][p]
  float* cwbuf = pprojT + (long)B_ * D_ * P_;  // 1280*512 {cproj,weff}
  bf16* wb = (bf16*)(cwbuf + MT * D_ * 2);     // bf16 weight arena
  bf16* w2Tb = wb + WB_TOTAL;                  // 256*256
  bf16* patb = w2Tb + D_ * D_;                 // 32*256*384
  bf16* hb = patb + (long)B_ * P_ * DINO_;     // 1280*1024 bf16

  // 1. prep jobs + qkv(l=0) with embed folded; x-block0 writes x (embed, f32)
  pq_k<<<960 + 64 + CONV_BLOCKS + PAT_BLOCKS, 256, 0, stream>>>(
      tokens, tok_emb, pos_emb, x, fus_w2, w2Tb, qkv_w, out_w, w1, w2, fus_w1,
      wb, patches, patb, qkv_b, qkvbuf);

  // 2. attn(l=0) + pproj (encoder-independent, fills idle CUs)
  attnp_k<<<256 + 2048, 256, 0, stream>>>(qkvbuf, attbuf, patb, wb + OFF_FUS,
                                          pprojT);

  // 3. out-proj(l=0) (+resid=x) + weff (encoder-independent)
  ow_k<<<dim3(8, 80), 256, 0, stream>>>(attbuf, wb + OFF_OUTW, out_b, x, s,
                                        cls_w, w2Tb, tokens, cwbuf);

  // 4. w1(l=0): LN1 folded into staging; x-block0 writes x = LN1(s)
  gemm_k<2, 1, 1, 0, 1, 0><<<dim3(32, 40), 256, 0, stream>>>(
      s, wb + OFF_W1, b1, nullptr, ln1_s, ln1_b, nullptr, x, hb, 256, 256, 256,
      DFF_);
  // 5. w2(l=0): s = hb @ w2^T + b2 + x
  gemm_k<1, 0, 0, 1, 0, 0><<<dim3(8, 40), 256, 0, stream>>>(
      hb, wb + OFF_W2, b2, x, nullptr, nullptr, nullptr, nullptr, s, DFF_,
      DFF_, DFF_, D_);
  // 6. qkv(l=1): LN2(l=0) folded; x-block0 writes x = LN2(s)
  gemm_k<2, 0, 0, 0, 1, 0><<<dim3(24, 40), 256, 0, stream>>>(
      s, wb + OFF_QKV + 3 * D_ * D_, qkv_b + 3 * D_, nullptr, ln2_s, ln2_b,
      nullptr, x, qkvbuf, 256, 256, 256, 3 * D_);
  // 7. attn(l=1)
  attnp_k<<<256, 256, 0, stream>>>(qkvbuf, attbuf, patb, wb + OFF_FUS, pprojT);
  // 8. out-proj(l=1) + resid=x
  gemm_k<0, 0, 0, 1, 0, 0><<<dim3(8, 40), 256, 0, stream>>>(
      attbuf, wb + OFF_OUTW + D_ * D_, out_b + D_, x, nullptr, nullptr,
      nullptr, nullptr, s, 256, 256, 256, D_);
  // 9. w1(l=1): LN1(l=1) folded; writes x
  gemm_k<2, 1, 1, 0, 1, 0><<<dim3(32, 40), 256, 0, stream>>>(
      s, wb + OFF_W1 + DFF_ * D_, b1 + DFF_, nullptr, ln1_s + D_, ln1_b + D_,
      nullptr, x, hb, 256, 256, 256, DFF_);
  // 10. w2(l=1)
  gemm_k<1, 0, 0, 1, 0, 0><<<dim3(8, 40), 256, 0, stream>>>(
      hb, wb + OFF_W2 + D_ * DFF_, b2 + D_, x, nullptr, nullptr, nullptr,
      nullptr, s, DFF_, DFF_, DFF_, D_);

  // 11. cproj: shifted LN2(l=1) folded into staging -> cw even (+fus_b1)
  gemm_k<4, 0, 0, 0, 0, 1><<<dim3(8, 40), 256, 0, stream>>>(
      s, wb + OFF_FUS + DINO_, fus_b1, nullptr, ln2_s + D_, ln2_b + D_,
      nullptr, nullptr, cwbuf, 256, 256, 640, D_);

  // 12. final
  final_k<<<dim3(4, 10, 32), 256, 0, stream>>>(pprojT, cwbuf, tokens, cls_w,
                                               cls_b, fus_b2, out);
}

// Round 2
// 281.188 us; speedup vs baseline: 1.0080x; 1.0080x over previous
//
#include <hip/hip_runtime.h>
#include <hip/hip_bf16.h>

#define B_ 32
#define T_ 40
#define P_ 256
#define V_ 4096
#define D_ 256
#define DINO_ 384
#define H_ 4
#define L_ 2
#define HD_ 64
#define DFF_ 1024
#define EPS_ 1e-5f

typedef __bf16 bf16;
typedef __bf16 bf16x8 __attribute__((ext_vector_type(8)));
typedef float f32x4 __attribute__((ext_vector_type(4)));

// bf16 weight arena offsets (elements)
#define OFF_QKV 0            // 2 x 768*256
#define OFF_OUTW 393216      // 2 x 256*256
#define OFF_W1 524288        // 2 x 1024*256
#define OFF_W2 1048576       // 2 x 256*1024
#define OFF_FUS 1572864      // 256*640
#define WB_TOTAL 1736704
#define CONV_BLOCKS 848      // WB_TOTAL / 2048
#define PAT_BLOCKS 1536      // 32*256*384 / 2048

__device__ __forceinline__ bf16x8 cvt8(const float* p) {
  float4 f0 = *(const float4*)p;
  float4 f1 = *(const float4*)(p + 4);
  bf16x8 v;
  v[0] = (bf16)f0.x; v[1] = (bf16)f0.y; v[2] = (bf16)f0.z; v[3] = (bf16)f0.w;
  v[4] = (bf16)f1.x; v[5] = (bf16)f1.y; v[6] = (bf16)f1.z; v[7] = (bf16)f1.w;
  return v;
}

// ---------------------------------------------------------------------------
// 32x32-tile MFMA GEMM body, KP=128 LDS panels (17.4 KB -> 8 blocks/CU).
// ASRC: 0=f32 A, 1=bf16 A, 2=LN-fold(f32 rows, full-width A panel),
// 3=token-gather f32 rows, 4=shifted-LN-fold (cproj), 5=embed-fold.
// WF32: W staged from f32. CW: 0 normal, 1 cw-even(+bias), 2 cw-odd.
// xout!=nullptr (ASRC 2/5): also write staged fp32 rows (residual path).
// ---------------------------------------------------------------------------
template <int ASRC, int WF32, int OBF16, int RELU, int RESID, int CW>
__device__ __forceinline__ void gemm_body(
    bf16* As, bf16* Ws, const void* Av, const void* Wv, const float* bias,
    const float* resid, const float* aux0, const float* aux1,
    const int* tokens, float* xout, void* outv, int K, int lda, int ldw,
    int ldc, int bm, int bn) {
  const int LDW = 136;
  const int AFULL = (ASRC == 2 || ASRC == 4);
  const int LDA = AFULL ? 264 : 136;
  const int tid = threadIdx.x;
  const int lane = tid & 63;
  const int wv = tid >> 6;
  const int mi = wv & 1, ni = wv >> 1;
  const int col = lane & 15, quad = lane >> 4;
  const int srow = tid >> 3, kc = (tid & 7) * 8;
  const int gm = bm + srow;
  f32x4 acc = {0.f, 0.f, 0.f, 0.f};

  const float* Af = (const float*)Av;
  const bf16* Ab = (const bf16*)Av;
  const float* Wf = (const float*)Wv;
  const bf16* Wb = (const bf16*)Wv;

  const float* te = nullptr;
  const float* pe = nullptr;
  const float* Ag = nullptr;
  if (ASRC == 5) {
    te = Af + (long)tokens[gm] * D_;
    pe = aux0 + (gm % T_) * D_;
  }
  if (ASRC == 3) Ag = Af + (long)tokens[gm] * D_;

  if (AFULL) {
    // LN over the full 256-col row, 8 threads/row, staged straight to LDS.
    const int cg = (tid & 7) * 32;
    bool zero = false;
    long srcrow = gm;
    if (ASRC == 4) {
      if (gm % T_ == 0) zero = true;
      srcrow = gm - 1;
    }
    if (zero) {
      bf16x8 z8 = {};
#pragma unroll
      for (int i = 0; i < 4; ++i) *(bf16x8*)&As[srow * LDA + cg + i * 8] = z8;
    } else {
      const float* sp = Af + srcrow * D_ + cg;
      float v[32];
      float sum = 0.f, ss = 0.f;
#pragma unroll
      for (int i = 0; i < 8; ++i) {
        float4 f = *(const float4*)(sp + i * 4);
        v[i * 4] = f.x; v[i * 4 + 1] = f.y; v[i * 4 + 2] = f.z; v[i * 4 + 3] = f.w;
        sum += f.x + f.y + f.z + f.w;
        ss += f.x * f.x + f.y * f.y + f.z * f.z + f.w * f.w;
      }
#pragma unroll
      for (int mk = 1; mk < 8; mk <<= 1) {
        sum += __shfl_xor(sum, mk);
        ss += __shfl_xor(ss, mk);
      }
      float mean = sum * (1.0f / D_);
      float inv = rsqrtf(ss * (1.0f / D_) - mean * mean + EPS_);
#pragma unroll
      for (int i = 0; i < 32; ++i) {
        float o = (v[i] - mean) * inv * aux0[cg + i] + aux1[cg + i];
        As[srow * LDA + cg + i] = (bf16)o;
        v[i] = o;
      }
      if (ASRC == 2 && xout) {
#pragma unroll
        for (int i = 0; i < 8; ++i)
          *(float4*)(xout + (long)gm * D_ + cg + i * 4) =
              make_float4(v[i * 4], v[i * 4 + 1], v[i * 4 + 2], v[i * 4 + 3]);
      }
    }
  }

  for (int kk0 = 0; kk0 < K; kk0 += 128) {
    if (ASRC == 0) {
#pragma unroll
      for (int h = 0; h < 2; ++h)
        *(bf16x8*)&As[srow * LDA + h * 64 + kc] =
            cvt8(Af + (long)gm * lda + kk0 + h * 64 + kc);
    } else if (ASRC == 1) {
#pragma unroll
      for (int h = 0; h < 2; ++h)
        *(bf16x8*)&As[srow * LDA + h * 64 + kc] =
            *(const bf16x8*)(Ab + (long)gm * lda + kk0 + h * 64 + kc);
    } else if (ASRC == 3) {
#pragma unroll
      for (int h = 0; h < 2; ++h)
        *(bf16x8*)&As[srow * LDA + h * 64 + kc] = cvt8(Ag + kk0 + h * 64 + kc);
    } else if (ASRC == 5) {
#pragma unroll
      for (int h = 0; h < 2; ++h) {
        int gc = kk0 + h * 64 + kc;
        float4 e0 = *(const float4*)(te + gc), e1 = *(const float4*)(te + gc + 4);
        float4 p0 = *(const float4*)(pe + gc), p1 = *(const float4*)(pe + gc + 4);
        float o0 = e0.x + p0.x, o1 = e0.y + p0.y, o2 = e0.z + p0.z, o3 = e0.w + p0.w;
        float o4 = e1.x + p1.x, o5 = e1.y + p1.y, o6 = e1.z + p1.z, o7 = e1.w + p1.w;
        bf16x8 vv;
        vv[0] = (bf16)o0; vv[1] = (bf16)o1; vv[2] = (bf16)o2; vv[3] = (bf16)o3;
        vv[4] = (bf16)o4; vv[5] = (bf16)o5; vv[6] = (bf16)o6; vv[7] = (bf16)o7;
        *(bf16x8*)&As[srow * LDA + h * 64 + kc] = vv;
        if (xout) {
          *(float4*)(xout + (long)gm * D_ + gc) = make_float4(o0, o1, o2, o3);
          *(float4*)(xout + (long)gm * D_ + gc + 4) = make_float4(o4, o5, o6, o7);
        }
      }
    }
    if (WF32) {
#pragma unroll
      for (int h = 0; h < 2; ++h)
        *(bf16x8*)&Ws[srow * LDW + h * 64 + kc] =
            cvt8(Wf + (long)(bn + srow) * ldw + kk0 + h * 64 + kc);
    } else {
#pragma unroll
      for (int h = 0; h < 2; ++h)
        *(bf16x8*)&Ws[srow * LDW + h * 64 + kc] =
            *(const bf16x8*)(Wb + (long)(bn + srow) * ldw + kk0 + h * 64 + kc);
    }
    __syncthreads();
#pragma unroll
    for (int ki = 0; ki < 4; ++ki) {
      const int ak = AFULL ? (kk0 + ki * 32) : (ki * 32);
      bf16x8 afr = *(const bf16x8*)&As[(mi * 16 + col) * LDA + ak + quad * 8];
      bf16x8 bfr = *(const bf16x8*)&Ws[(ni * 16 + col) * LDW + ki * 32 + quad * 8];
      acc = __builtin_amdgcn_mfma_f32_16x16x32_bf16(afr, bfr, acc, 0, 0, 0);
    }
    if (kk0 + 128 < K) __syncthreads();
  }

  const int n = bn + ni * 16 + col;
  float bv = bias ? bias[n] : 0.0f;
#pragma unroll
  for (int r = 0; r < 4; ++r) {
    int m = bm + mi * 16 + quad * 4 + r;
    float val = acc[r] + bv;
    if (RESID) val += resid[(long)m * D_ + n];
    if (RELU) val = fmaxf(val, 0.0f);
    if (CW == 1) ((float*)outv)[(long)m * (2 * D_) + n * 2] = val;
    else if (CW == 2) ((float*)outv)[(long)m * (2 * D_) + n * 2 + 1] = val;
    else if (OBF16) ((bf16*)outv)[(long)m * ldc + n] = (bf16)val;
    else ((float*)outv)[(long)m * ldc + n] = val;
  }
}

// shared-memory shapes
struct __align__(16) AttnSM { float q[20][65]; float k[40][65]; float v[40][65]; float s[20][41]; };
struct __align__(16) Gemm128SM { bf16 As[32 * 136]; bf16 Ws[32 * 136]; };  // 17408 B
struct __align__(16) GemmLNSM  { bf16 As[32 * 264]; bf16 Ws[32 * 136]; };  // 25600 B
struct __align__(16) PrepSM { float tile[32][33]; };
union __align__(16) APSM { AttnSM a; Gemm128SM g; };   // 29280 B -> 5 blk/CU
union __align__(16) PQSM { PrepSM p; Gemm128SM g; };   // 17408 B -> 8 blk/CU

// ---- generic standalone GEMM wrapper --------------------------------------
template <int ASRC, int OBF16, int RELU, int RESID, int XW, int CW>
__global__ __launch_bounds__(256) void gemm_k(
    const void* __restrict__ Av, const void* __restrict__ Wv,
    const float* __restrict__ bias, const float* __restrict__ resid,
    const float* __restrict__ aux0, const float* __restrict__ aux1,
    const int* __restrict__ tokens, float* __restrict__ xw,
    void* __restrict__ outv, int K, int lda, int ldw, int ldc) {
  float* xo = (XW && blockIdx.x == 0) ? xw : nullptr;
  if constexpr (ASRC == 2 || ASRC == 4) {
    __shared__ GemmLNSM sm;
    gemm_body<ASRC, 0, OBF16, RELU, RESID, CW>(
        sm.As, sm.Ws, Av, Wv, bias, resid, aux0, aux1, tokens, xo, outv, K,
        lda, ldw, ldc, blockIdx.y * 32, blockIdx.x * 32);
  } else {
    __shared__ Gemm128SM sm;
    gemm_body<ASRC, 0, OBF16, RELU, RESID, CW>(
        sm.As, sm.Ws, Av, Wv, bias, resid, aux0, aux1, tokens, xo, outv, K,
        lda, ldw, ldc, blockIdx.y * 32, blockIdx.x * 32);
  }
}

// ---- prep jobs merged with qkv0 (embed folded into staging) ---------------
__global__ __launch_bounds__(256) void pq_k(
    const int* __restrict__ tokens, const float* __restrict__ tok_emb,
    const float* __restrict__ pos_emb, float* __restrict__ x,
    const float* __restrict__ fus_w2, bf16* __restrict__ w2Tb,
    const float* __restrict__ qkv_w, const float* __restrict__ out_w,
    const float* __restrict__ w1, const float* __restrict__ w2,
    const float* __restrict__ fus_w1, bf16* __restrict__ wb,
    const float* __restrict__ patches, bf16* __restrict__ patb,
    const float* __restrict__ qkv_b, float* __restrict__ qkvbuf) {
  __shared__ PQSM sm;
  int bid = blockIdx.x;
  int tid = threadIdx.x;
  if (bid < 960) {
    // qkv layer 0: A = tok_emb gather + pos_emb (embed fold), W = fp32 qkv_w
    int bnb = bid % 24;
    gemm_body<5, 1, 0, 0, 0, 0>(
        sm.g.As, sm.g.Ws, tok_emb, qkv_w, qkv_b, nullptr, pos_emb, nullptr,
        tokens, (bnb == 0) ? x : nullptr, qkvbuf, 256, 256, 256, 3 * D_,
        (bid / 24) * 32, bnb * 32);
    return;
  }
  int bi = bid - 960;
  if (bi < 64) {
    int bx = (bi & 7) * 32, by = (bi >> 3) * 32;
    int tx = tid & 31, ty = tid >> 5;  // 32 x 8
#pragma unroll
    for (int i = 0; i < 32; i += 8)
      sm.p.tile[ty + i][tx] = fus_w2[(by + ty + i) * D_ + bx + tx];
    __syncthreads();
#pragma unroll
    for (int i = 0; i < 32; i += 8)
      w2Tb[(bx + ty + i) * D_ + by + tx] = (bf16)sm.p.tile[tx][ty + i];
  } else if (bi < 64 + CONV_BLOCKS) {
    long f = (long)(bi - 64) * 2048 + tid * 8;
    const float* src;
    long off;
    if (f < OFF_OUTW)      { src = qkv_w;  off = f - OFF_QKV; }
    else if (f < OFF_W1)   { src = out_w;  off = f - OFF_OUTW; }
    else if (f < OFF_W2)   { src = w1;     off = f - OFF_W1; }
    else if (f < OFF_FUS)  { src = w2;     off = f - OFF_W2; }
    else                   { src = fus_w1; off = f - OFF_FUS; }
    *(bf16x8*)&wb[f] = cvt8(src + off);
  } else {
    long f = (long)(bi - 64 - CONV_BLOCKS) * 2048 + tid * 8;
    *(bf16x8*)&patb[f] = cvt8(patches + f);
  }
}

// ---- attention (+ optional co-launched pproj GEMM blocks) -----------------
__global__ __launch_bounds__(256) void attnp_k(
    const float* __restrict__ qkv, float* __restrict__ ctx,
    const bf16* __restrict__ patb, const bf16* __restrict__ fusb,
    float* __restrict__ pprojT) {
  __shared__ APSM sm;
  int bid = blockIdx.x;
  int tid = threadIdx.x;
  if (bid >= 256) {
    // pproj: C[e][p] = fus_w1_patch @ patb[b]^T  (independent of encoder)
    int g = bid - 256;
    int bn = (g & 7) * 32;
    int y = g >> 3;
    int bb = y >> 3, bm = (y & 7) * 32;
    gemm_body<1, 0, 0, 0, 0, 0>(
        sm.g.As, sm.g.Ws, fusb, patb + (long)bb * P_ * DINO_, nullptr, nullptr,
        nullptr, nullptr, nullptr, nullptr, pprojT + (long)bb * D_ * P_, 384,
        640, DINO_, P_, bm, bn);
    return;
  }
  int h = bid & 3, b = (bid >> 2) & 31, zq = bid >> 7;
  int r0 = zq * 20;
  int lane = tid & 63, wv = tid >> 6;
  float (&q)[20][65] = sm.a.q;
  float (&k)[40][65] = sm.a.k;
  float (&v)[40][65] = sm.a.v;
  float (&s)[20][41] = sm.a.s;
  for (int idx = tid; idx < T_ * HD_; idx += 256) {
    int t = idx >> 6, d = idx & 63;
    long base = (long)(b * T_ + t) * (3 * D_) + h * HD_ + d;
    k[t][d] = qkv[base + D_];
    v[t][d] = qkv[base + 2 * D_];
    if (t < 20) q[t][d] = qkv[(long)(b * T_ + r0 + t) * (3 * D_) + h * HD_ + d];
  }
  __syncthreads();
  for (int idx = tid; idx < 20 * T_; idx += 256) {
    int i = idx / T_, j = idx - i * T_;
    if (j <= r0 + i) {
      float acc = 0.f;
#pragma unroll
      for (int d = 0; d < HD_; ++d) acc += q[i][d] * k[j][d];
      s[i][j] = acc * 0.125f;
    }
  }
  __syncthreads();
  for (int rr = wv; rr < 20; rr += 4) {
    int hi = r0 + rr;
    float val = (lane <= hi) ? s[rr][lane] : -1e30f;
    float mx = val;
#pragma unroll
    for (int mk = 1; mk < 64; mk <<= 1) mx = fmaxf(mx, __shfl_xor(mx, mk));
    float e = (lane <= hi)
                  ? __builtin_amdgcn_exp2f((val - mx) * 1.4426950408889634f)
                  : 0.f;
    float sum = e;
#pragma unroll
    for (int mk = 1; mk < 64; mk <<= 1) sum += __shfl_xor(sum, mk);
    float inv = __builtin_amdgcn_rcpf(sum);
    if (lane < T_) s[rr][lane] = e * inv;
  }
  __syncthreads();
  for (int idx = tid; idx < 20 * HD_; idx += 256) {
    int i = idx >> 6, d = idx & 63;
    int hi = r0 + i;
    float acc = 0.f;
    for (int j = 0; j <= hi; ++j) acc += s[i][j] * v[j][d];
    ctx[(long)(b * T_ + hi) * D_ + h * HD_ + d] = acc;
  }
}

// ---- out-proj(l=0) + weff co-launched -------------------------------------
__global__ __launch_bounds__(256) void ow_k(
    const float* __restrict__ attb, const bf16* __restrict__ Wout,
    const float* __restrict__ outb, const float* __restrict__ xres,
    float* __restrict__ sbuf, const float* __restrict__ cls_w,
    const bf16* __restrict__ w2Tb, const int* __restrict__ tokens,
    float* __restrict__ cw) {
  __shared__ Gemm128SM sm;
  int y = blockIdx.y;
  if (y < 40)
    gemm_body<0, 0, 0, 0, 1, 0>(
        sm.As, sm.Ws, attb, Wout, outb, xres, nullptr, nullptr, nullptr,
        nullptr, sbuf, 256, 256, 256, 256, y * 32, blockIdx.x * 32);
  else
    gemm_body<3, 0, 0, 0, 0, 2>(
        sm.As, sm.Ws, cls_w, w2Tb, nullptr, nullptr, nullptr, nullptr, tokens,
        nullptr, cw, 256, 256, 256, 256, (y - 40) * 32, blockIdx.x * 32);
}

// ---- final: out[b,p,t] = sigmoid(sum_e gelu(pp+cp)*we + beff) -------------
__global__ __launch_bounds__(256) void final_k(const float* __restrict__ pprojT,
                                               const float* __restrict__ cw,
                                               const int* __restrict__ tokens,
                                               const float* __restrict__ cls_w,
                                               const float* __restrict__ cls_b,
                                               const float* __restrict__ fus_b2,
                                               float* __restrict__ out) {
  __shared__ float2 cws[4][D_];
  int tid = threadIdx.x;
  int lane = tid & 63, wv = tid >> 6;
  int p = blockIdx.x * 64 + lane;
  int t = blockIdx.y * 4 + wv;
  int b = blockIdx.z;
  int mbase = b * T_ + blockIdx.y * 4;
  for (int idx = tid; idx < 4 * D_; idx += 256) {
    int tt = idx >> 8, e = idx & 255;
    cws[tt][e] = ((const float2*)cw)[(long)(mbase + tt) * D_ + e];
  }
  __syncthreads();

  int m = b * T_ + t;
  int tok = tokens[m];
  const float* cr = cls_w + (long)tok * D_;
  float bacc = 0.f;
#pragma unroll
  for (int i = 0; i < 4; ++i) bacc += cr[lane + i * 64] * fus_b2[lane + i * 64];
#pragma unroll
  for (int mk = 1; mk < 64; mk <<= 1) bacc += __shfl_xor(bacc, mk);
  float beff = bacc + cls_b[tok];

  const float* ppb = pprojT + (long)b * (D_ * P_);  // [e][p]
  float acc = 0.f;
#pragma unroll 8
  for (int e = 0; e < D_; ++e) {
    float pp = ppb[e * P_ + p];
    float2 c = cws[wv][e];
    float x = pp + c.x;
    float ex = __builtin_amdgcn_exp2f(-2.4554248f * x);  // -1.702*log2e
    float r = __builtin_amdgcn_rcpf(1.0f + ex);
    acc = fmaf(x * r, c.y, acc);
  }
  float logit = acc + beff;
  float es = __builtin_amdgcn_exp2f(-1.4426950408889634f * logit);
  out[(long)(b * P_ + p) * T_ + t] = __builtin_amdgcn_rcpf(1.0f + es);
}

extern "C" void kernel_launch(void* const* d_in, const int* in_sizes, int n_in, void* d_out,
                              int out_size, void* d_ws, size_t ws_size, hipStream_t stream) {
  const float* patches = (const float*)d_in[0];
  const int* tokens = (const int*)d_in[1];
  const float* tok_emb = (const float*)d_in[2];
  const float* pos_emb = (const float*)d_in[3];
  const float* qkv_w = (const float*)d_in[4];
  const float* qkv_b = (const float*)d_in[5];
  const float* out_w = (const float*)d_in[6];
  const float* out_b = (const float*)d_in[7];
  const float* ln1_s = (const float*)d_in[8];
  const float* ln1_b = (const float*)d_in[9];
  const float* w1 = (const float*)d_in[10];
  const float* b1 = (const float*)d_in[11];
  const float* w2 = (const float*)d_in[12];
  const float* b2 = (const float*)d_in[13];
  const float* ln2_s = (const float*)d_in[14];
  const float* ln2_b = (const float*)d_in[15];
  const float* fus_w1 = (const float*)d_in[16];
  const float* fus_b1 = (const float*)d_in[17];
  const float* fus_w2 = (const float*)d_in[18];
  const float* fus_b2 = (const float*)d_in[19];
  const float* cls_w = (const float*)d_in[20];
  const float* cls_b = (const float*)d_in[21];
  float* out = (float*)d_out;

  const int MT = B_ * T_;  // 1280
  float* x = (float*)d_ws;                     // 1280*256 (embed / LN outs)
  float* qkvbuf = x + MT * D_;                 // 1280*768
  float* attbuf = qkvbuf + MT * 3 * D_;        // 1280*256
  float* s = attbuf + MT * D_;                 // 1280*256 (residual sums)
  float* pprojT = s + MT * D_;                 // 32*256*256 [b][e][p]
  float* cwbuf = pprojT + (long)B_ * D_ * P_;  // 1280*512 {cproj,weff}
  bf16* wb = (bf16*)(cwbuf + MT * D_ * 2);     // bf16 weight arena
  bf16* w2Tb = wb + WB_TOTAL;                  // 256*256
  bf16* patb = w2Tb + D_ * D_;                 // 32*256*384
  bf16* hb = patb + (long)B_ * P_ * DINO_;     // 1280*1024 bf16

  // 1. prep jobs + qkv(l=0) with embed folded; x-block0 writes x (embed, f32)
  pq_k<<<960 + 64 + CONV_BLOCKS + PAT_BLOCKS, 256, 0, stream>>>(
      tokens, tok_emb, pos_emb, x, fus_w2, w2Tb, qkv_w, out_w, w1, w2, fus_w1,
      wb, patches, patb, qkv_b, qkvbuf);

  // 2. attn(l=0) + pproj (encoder-independent, fills idle CUs)
  attnp_k<<<256 + 2048, 256, 0, stream>>>(qkvbuf, attbuf, patb, wb + OFF_FUS,
                                          pprojT);

  // 3. out-proj(l=0) (+resid=x) + weff (encoder-independent)
  ow_k<<<dim3(8, 80), 256, 0, stream>>>(attbuf, wb + OFF_OUTW, out_b, x, s,
                                        cls_w, w2Tb, tokens, cwbuf);

  // 4. w1(l=0): LN1 folded into staging; x-block0 writes x = LN1(s)
  gemm_k<2, 1, 1, 0, 1, 0><<<dim3(32, 40), 256, 0, stream>>>(
      s, wb + OFF_W1, b1, nullptr, ln1_s, ln1_b, nullptr, x, hb, 256, 256, 256,
      DFF_);
  // 5. w2(l=0): s = hb @ w2^T + b2 + x
  gemm_k<1, 0, 0, 1, 0, 0><<<dim3(8, 40), 256, 0, stream>>>(
      hb, wb + OFF_W2, b2, x, nullptr, nullptr, nullptr, nullptr, s, DFF_,
      DFF_, DFF_, D_);
  // 6. qkv(l=1): LN2(l=0) folded; x-block0 writes x = LN2(s)
  gemm_k<2, 0, 0, 0, 1, 0><<<dim3(24, 40), 256, 0, stream>>>(
      s, wb + OFF_QKV + 3 * D_ * D_, qkv_b + 3 * D_, nullptr, ln2_s, ln2_b,
      nullptr, x, qkvbuf, 256, 256, 256, 3 * D_);
  // 7. attn(l=1)
  attnp_k<<<256, 256, 0, stream>>>(qkvbuf, attbuf, patb, wb + OFF_FUS, pprojT);
  // 8. out-proj(l=1) + resid=x
  gemm_k<0, 0, 0, 1, 0, 0><<<dim3(8, 40), 256, 0, stream>>>(
      attbuf, wb + OFF_OUTW + D_ * D_, out_b + D_, x, nullptr, nullptr,
      nullptr, nullptr, s, 256, 256, 256, D_);
  // 9. w1(l=1): LN1(l=1) folded; writes x
  gemm_k<2, 1, 1, 0, 1, 0><<<dim3(32, 40), 256, 0, stream>>>(
      s, wb + OFF_W1 + DFF_ * D_, b1 + DFF_, nullptr, ln1_s + D_, ln1_b + D_,
      nullptr, x, hb, 256, 256, 256, DFF_);
  // 10. w2(l=1)
  gemm_k<1, 0, 0, 1, 0, 0><<<dim3(8, 40), 256, 0, stream>>>(
      hb, wb + OFF_W2 + D_ * DFF_, b2 + D_, x, nullptr, nullptr, nullptr,
      nullptr, s, DFF_, DFF_, DFF_, D_);

  // 11. cproj: shifted LN2(l=1) folded into staging -> cw even (+fus_b1)
  gemm_k<4, 0, 0, 0, 0, 1><<<dim3(8, 40), 256, 0, stream>>>(
      s, wb + OFF_FUS + DINO_, fus_b1, nullptr, ln2_s + D_, ln2_b + D_,
      nullptr, nullptr, cwbuf, 256, 256, 640, D_);

  // 12. final
  final_k<<<dim3(4, 10, 32), 256, 0, stream>>>(pprojT, cwbuf, tokens, cls_w,
                                               cls_b, fus_b2, out);
}